// Round 4
// baseline (50.895 us; speedup 1.0000x reference)
//
#include <hip/hip_runtime.h>

#define BSZ    64
#define NF     4
#define NCLS   4
#define PLO    256
#define PHI    16384
#define KN     9
#define W27    27
#define SPLITS 3

__global__ __launch_bounds__(256, 3) void rect_up_kernel(
    const float* __restrict__ x,         // (B, NF*PLO)
    const float* __restrict__ orog,      // (B, PHI, 2)
    const float* __restrict__ wmap,      // (NCLS, NF, PHI, KN, 3)
    const float* __restrict__ bias_low,  // (NCLS, NF, PLO)
    const float* __restrict__ bias_high, // (NCLS, NF, PHI)
    const float* __restrict__ bias_orog, // (NCLS, 2, PHI)
    const int*   __restrict__ cls_ids,   // (B,)
    const int*   __restrict__ nb,        // (PHI, KN)
    float* __restrict__ out)             // (B, NF, PHI)
{
    // per-wave private staging regions -> no __syncthreads anywhere
    __shared__ float wstage[4][64 * W27];   // 27648 B

    const int bid   = blockIdx.x;
    const int cls   = bid & (NCLS - 1);
    const int chunk = (bid >> 2) & 63;
    const int split = bid >> 8;             // 0..SPLITS-1
    const int t     = threadIdx.x;
    const int wave  = t >> 6;
    const int lane  = t & 63;
    const int p     = chunk * 256 + t;

    // ---- class membership mask (wave width == BSZ == 64) ---------------
    const unsigned long long cmask = __ballot(cls_ids[lane] == cls);

    // ---- batch-invariant neighbor geometry -----------------------------
    const int pi = p >> 7, pj = p & 127;
    const int cr0 = (pi - 2 < 0 ? 0 : pi - 2) >> 3;
    const int cr1 = (pi + 2 > 127 ? 127 : pi + 2) >> 3;
    const int cc0 = (pj - 2 < 0 ? 0 : pj - 2) >> 3;
    const int cc1 = (pj + 2 > 127 ? 127 : pj + 2) >> 3;
    int cells[4];
    cells[0] = cr0 * 16 + cc0;  cells[1] = cr0 * 16 + cc1;
    cells[2] = cr1 * 16 + cc0;  cells[3] = cr1 * 16 + cc1;

    int nbOff[KN], sel[KN];
    #pragma unroll
    for (int k = 0; k < KN; ++k) {
        const int n = nb[p * KN + k];
        nbOff[k] = n * 8;
        sel[k] = (((n >> 7) >> 3) != cr0 ? 2 : 0) | (((n & 127) >> 3) != cc0 ? 1 : 0);
    }

    // ---- batch scan state ----------------------------------------------
    unsigned long long m = cmask;
    int ord = 0;
    auto nextb = [&]() -> int {
        while (m) {
            const int b = __ffsll((unsigned long long)m) - 1;
            m &= m - 1;
            const bool take = (ord == split);
            ord = (ord + 1 == SPLITS) ? 0 : ord + 1;
            if (take) return b;
        }
        return -1;
    };

    int b = nextb();
    if (b < 0) return;                      // uniform across block

    // ---- prefetch first batch's orog BEFORE weight staging -------------
    float o0[KN], o1[KN];
    {
        const char* ob = (const char*)orog + (size_t)b * (PHI * 8);
        #pragma unroll
        for (int k = 0; k < KN; ++k) {
            const float2 v = *reinterpret_cast<const float2*>(ob + nbOff[k]);
            o0[k] = v.x; o1[k] = v.y;
        }
    }

    // ---- early bias loads (independent of weights) ---------------------
    float yob0[KN], yob1[KN];
    #pragma unroll
    for (int k = 0; k < KN; ++k) {
        const int n = nbOff[k] >> 3;
        yob0[k] = bias_orog[(cls * 2 + 0) * PHI + n];
        yob1[k] = bias_orog[(cls * 2 + 1) * PHI + n];
    }
    float bh[NF], blv[NF][4];
    #pragma unroll
    for (int f = 0; f < NF; ++f) {
        bh[f] = bias_high[(cls * NF + f) * PHI + p];
        #pragma unroll
        for (int j = 0; j < 4; ++j)
            blv[f][j] = bias_low[(cls * NF + f) * PLO + cells[j]];
    }

    // ---- weights: per-wave coalesced float4 -> LDS -> regs -------------
    float wcy[NF][4], w1[NF][KN], w2[NF][KN];
    #pragma unroll
    for (int f = 0; f < NF; ++f) {
        const float4* s4 = reinterpret_cast<const float4*>(
            wmap + ((size_t)(cls * NF + f) * PHI + chunk * 256 + wave * 64) * W27);
        float4* d4 = reinterpret_cast<float4*>(&wstage[wave][0]);
        #pragma unroll
        for (int i2 = 0; i2 < 7; ++i2) {
            const int idx = lane + i2 * 64;        // 432 float4 per wave
            if (idx < (64 * W27) / 4) d4[idx] = s4[idx];
        }
        // wave-local RAW: DS ops are wave-ordered; compiler inserts lgkmcnt
        #pragma unroll
        for (int j = 0; j < 4; ++j) wcy[f][j] = 0.0f;
        #pragma unroll
        for (int k = 0; k < KN; ++k) {
            const float w0 = wstage[wave][lane * W27 + 3 * k];
            w1[f][k] = wstage[wave][lane * W27 + 3 * k + 1];
            w2[f][k] = wstage[wave][lane * W27 + 3 * k + 2];
            #pragma unroll
            for (int j = 0; j < 4; ++j)
                wcy[f][j] += (sel[k] == j) ? w0 : 0.0f;
        }
    }

    // ---- fold biases into accumulator init -----------------------------
    float accInit[NF];
    #pragma unroll
    for (int f = 0; f < NF; ++f) {
        float a = bh[f];
        #pragma unroll
        for (int k = 0; k < KN; ++k)
            a -= yob0[k] * w1[f][k] + yob1[k] * w2[f][k];
        #pragma unroll
        for (int j = 0; j < 4; ++j)
            a -= blv[f][j] * wcy[f][j];
        accInit[f] = a;
    }

    // ---- batch loop: barrier-free, orog prefetched one batch ahead -----
    while (true) {
        const int bn = nextb();
        float n0[KN], n1[KN];
        if (bn >= 0) {
            const char* ob = (const char*)orog + (size_t)bn * (PHI * 8);
            #pragma unroll
            for (int k = 0; k < KN; ++k) {
                const float2 v = *reinterpret_cast<const float2*>(ob + nbOff[k]);
                n0[k] = v.x; n1[k] = v.y;
            }
        }

        const float* xb = x + b * (NF * PLO);
        #pragma unroll
        for (int f = 0; f < NF; ++f) {
            float acc = accInit[f];
            #pragma unroll
            for (int j = 0; j < 4; ++j)
                acc += xb[f * PLO + cells[j]] * wcy[f][j];
            #pragma unroll
            for (int k = 0; k < KN; ++k)
                acc += o0[k] * w1[f][k] + o1[k] * w2[f][k];
            __builtin_nontemporal_store(acc, &out[((size_t)b * NF + f) * PHI + p]);
        }

        if (bn < 0) break;
        b = bn;
        #pragma unroll
        for (int k = 0; k < KN; ++k) { o0[k] = n0[k]; o1[k] = n1[k]; }
    }
}

extern "C" void kernel_launch(void* const* d_in, const int* in_sizes, int n_in,
                              void* d_out, int out_size, void* d_ws, size_t ws_size,
                              hipStream_t stream) {
    const float* x         = (const float*)d_in[0];
    const float* orog      = (const float*)d_in[1];
    const float* wmap      = (const float*)d_in[2];
    const float* bias_low  = (const float*)d_in[3];
    const float* bias_high = (const float*)d_in[4];
    const float* bias_orog = (const float*)d_in[5];
    const int*   cls_ids   = (const int*)d_in[6];
    const int*   nb        = (const int*)d_in[7];
    float* out = (float*)d_out;

    // grid: NCLS classes x 64 p-chunks x SPLITS batch-splits = 768 blocks
    dim3 grid(NCLS * (PHI / 256) * SPLITS);
    dim3 block(256);
    rect_up_kernel<<<grid, block, 0, stream>>>(
        x, orog, wmap, bias_low, bias_high, bias_orog, cls_ids, nb, out);
}